// Round 7
// baseline (175.787 us; speedup 1.0000x reference)
//
#include <hip/hip_runtime.h>

typedef __attribute__((ext_vector_type(4))) float f32x4;
typedef __attribute__((ext_vector_type(8))) __bf16 bf16x8;
typedef __attribute__((ext_vector_type(8))) unsigned short us8;

__device__ __forceinline__ unsigned short f2bf(float f) {
    unsigned u = __builtin_bit_cast(unsigned, f);
    u += 0x7fffu + ((u >> 16) & 1u);
    return (unsigned short)(u >> 16);
}

__device__ __forceinline__ float exp2v(float x) {
    float r;
    asm("v_exp_f32 %0, %1" : "=v"(r) : "v"(x));
    return r;
}

__device__ __forceinline__ f32x4 mfma16(bf16x8 a, bf16x8 b, f32x4 c) {
    return __builtin_amdgcn_mfma_f32_16x16x32_bf16(a, b, c, 0, 0, 0);
}

__device__ __forceinline__ void gload16(const void* g, void* l) {
    __builtin_amdgcn_global_load_lds(
        (const __attribute__((address_space(1))) unsigned int*)g,
        (__attribute__((address_space(3))) unsigned int*)l, 16, 0, 0);
}

// ------------- fp32 -> bf16 convert, both inputs in one launch ---------------
__global__ __launch_bounds__(256) void conv2_bf16(const float* __restrict__ a,
                                                  unsigned short* __restrict__ oa,
                                                  int na8,
                                                  const float* __restrict__ b,
                                                  unsigned short* __restrict__ ob,
                                                  int nb8) {
    int i = blockIdx.x * 256 + threadIdx.x;
    const float* in;
    unsigned short* out;
    if (i < na8) {
        in = a; out = oa;
    } else {
        i -= na8;
        if (i >= nb8) return;
        in = b; out = ob;
    }
    const float4* p = (const float4*)in + (size_t)i * 2;
    float4 x = p[0], y = p[1];
    us8 o;
    o[0] = f2bf(x.x); o[1] = f2bf(x.y); o[2] = f2bf(x.z); o[3] = f2bf(x.w);
    o[4] = f2bf(y.x); o[5] = f2bf(y.y); o[6] = f2bf(y.z); o[7] = f2bf(y.w);
    *((us8*)out + i) = o;
}

// ------ all 4 weights: fp32 [R][1024] -> bf16 [1024][R], one launch ---------
__global__ __launch_bounds__(256) void wtrans_all(const float* __restrict__ Wq,
                                                  const float* __restrict__ Wk,
                                                  const float* __restrict__ Wv,
                                                  const float* __restrict__ Wo,
                                                  unsigned short* __restrict__ WqT,
                                                  unsigned short* __restrict__ WkT,
                                                  unsigned short* __restrict__ WvT,
                                                  unsigned short* __restrict__ WoT,
                                                  float qscale) {
    __shared__ float t[32][33];
    int y = blockIdx.y;
    const float* in; unsigned short* out; int R; float scale = 1.0f;
    if (y < 32)      { in = Wq; out = WqT; R = 1024; scale = qscale; }
    else if (y < 56) { in = Wk; out = WkT; R = 768;  y -= 32; }
    else if (y < 80) { in = Wv; out = WvT; R = 768;  y -= 56; }
    else             { in = Wo; out = WoT; R = 1024; y -= 80; }
    int tx = threadIdx.x, ty = threadIdx.y;
    int r0 = y * 32, c0 = blockIdx.x * 32;
#pragma unroll
    for (int k = 0; k < 4; ++k)
        t[ty + k * 8][tx] = in[(size_t)(r0 + ty + k * 8) * 1024 + c0 + tx];
    __syncthreads();
#pragma unroll
    for (int k = 0; k < 4; ++k)
        out[(size_t)(c0 + ty + k * 8) * R + r0 + tx] = f2bf(t[tx][ty + k * 8] * scale);
}

// ---- merged Q/K/V projection, XCD-contiguous m-panels, 128x128 tiles -------
__global__ __launch_bounds__(256, 4) void proj_qkv(const unsigned short* __restrict__ qbf,
                                                   const unsigned short* __restrict__ kvbf,
                                                   const unsigned short* __restrict__ WqT,
                                                   const unsigned short* __restrict__ WkT,
                                                   const unsigned short* __restrict__ WvT,
                                                   unsigned short* __restrict__ Qh,
                                                   unsigned short* __restrict__ Kh,
                                                   unsigned short* __restrict__ VTh) {
    __shared__ __align__(16) unsigned short SL[2][8192];
    const int id = blockIdx.x;
    const int xcd = id & 7, j = id >> 3;
    const int my = xcd * 8 + (j & 7);
    const int rest = j >> 3;          // 0..23
    const int op = rest >> 3;         // 0:Q 1:K 2:V
    const int nx = rest & 7;
    const int m0 = my * 128, n0 = nx * 128;
    const unsigned short* A = (op == 0) ? qbf : kvbf;
    const unsigned short* B = (op == 0) ? WqT : (op == 1 ? WkT : WvT);
    const int KD = (op == 0) ? 1024 : 768;
    const int NT = KD >> 5;

    const int tid = threadIdx.x;
    const int w = tid >> 6, l = tid & 63;
    const int lr = l & 15, lg = l >> 4;
    const int wm = (w >> 1) * 64, wn = (w & 1) * 64;

    f32x4 acc[4][4] = {};

    int ci0 = w * 64 + l;
    int r0 = ci0 >> 2, c0 = (ci0 & 3) ^ (r0 & 3);
    int ci1 = 256 + ci0;
    int r1 = ci1 >> 2, c1 = (ci1 & 3) ^ (r1 & 3);

    const unsigned short* Ag0 = A + (size_t)(m0 + r0) * KD + c0 * 8;
    const unsigned short* Ag1 = A + (size_t)(m0 + r1) * KD + c1 * 8;
    const unsigned short* Bg0 = B + (size_t)(n0 + r0) * KD + c0 * 8;
    const unsigned short* Bg1 = B + (size_t)(n0 + r1) * KD + c1 * 8;

#define STG(buf, k0)                                                  \
    do {                                                              \
        gload16(Ag0 + (k0), &SL[buf][w * 512]);                       \
        gload16(Ag1 + (k0), &SL[buf][2048 + w * 512]);                \
        gload16(Bg0 + (k0), &SL[buf][4096 + w * 512]);                \
        gload16(Bg1 + (k0), &SL[buf][4096 + 2048 + w * 512]);         \
    } while (0)

    STG(0, 0);
    int buf = 0;
    for (int kt = 0; kt < NT; ++kt) {
        if (kt + 1 < NT) {
            STG(buf ^ 1, (kt + 1) * 32);
            asm volatile("s_waitcnt vmcnt(4)" ::: "memory");
        } else {
            asm volatile("s_waitcnt vmcnt(0)" ::: "memory");
        }
        __builtin_amdgcn_s_barrier();
        const unsigned short* Alc = &SL[buf][0];
        const unsigned short* Blc = &SL[buf][4096];
        bf16x8 af[4], bfr[4];
#pragma unroll
        for (int t = 0; t < 4; ++t) {
            int ar = wm + t * 16 + lr;
            af[t] = *(const bf16x8*)&Alc[ar * 32 + ((lg ^ (ar & 3)) * 8)];
            int br = wn + t * 16 + lr;
            bfr[t] = *(const bf16x8*)&Blc[br * 32 + ((lg ^ (br & 3)) * 8)];
        }
#pragma unroll
        for (int i = 0; i < 4; ++i)
#pragma unroll
            for (int jj = 0; jj < 4; ++jj)
                acc[i][jj] = mfma16(af[i], bfr[jj], acc[i][jj]);
        __builtin_amdgcn_s_barrier();
        buf ^= 1;
    }
#undef STG

    if (op != 2) {
        unsigned short* Cout = (op == 0) ? Qh : Kh;
#pragma unroll
        for (int i = 0; i < 4; ++i)
#pragma unroll
            for (int jj = 0; jj < 4; ++jj)
#pragma unroll
                for (int r = 0; r < 4; ++r) {
                    int m = m0 + wm + i * 16 + lg * 4 + r;
                    int n = n0 + wn + jj * 16 + lr;
                    int b = m >> 11, ql = m & 2047, h = n >> 6, d = n & 63;
                    Cout[(((size_t)(b * 16 + h) * 2048 + ql) << 6) + d] = f2bf(acc[i][jj][r]);
                }
    } else {
        // V: transpose via LDS -> VT [bh][64d][2048kv], pi-permuted on kv.
        const int b = m0 >> 11;
        const int mloc = m0 & 2047;
        const int h0 = n0 >> 6;
#pragma unroll
        for (int hp = 0; hp < 2; ++hp) {
            unsigned short* VTb = VTh + (size_t)(b * 16 + h0 + hp) * (64 * 2048);
#pragma unroll
            for (int dh = 0; dh < 2; ++dh) {
                __syncthreads();
                if ((w & 1) == hp) {
#pragma unroll
                    for (int jj = 0; jj < 2; ++jj) {
                        int jc = dh * 2 + jj;
                        int dl = jj * 16 + lr;
#pragma unroll
                        for (int i = 0; i < 4; ++i)
#pragma unroll
                            for (int r = 0; r < 4; ++r) {
                                int kvl = wm + i * 16 + lg * 4 + r;
                                int pl = (kvl & 0x60) | (((kvl >> 2) & 3) << 3) |
                                         (((kvl >> 4) & 1) << 2) | (kvl & 3);
                                SL[0][dl * 136 + pl] = f2bf(acc[i][jc][r]);
                            }
                    }
                }
                __syncthreads();
#pragma unroll
                for (int cc = 0; cc < 2; ++cc) {
                    int idx = cc * 256 + tid;
                    int row = idx >> 4, col = (idx & 15) * 8;
                    *(us8*)&VTb[(size_t)(dh * 32 + row) * 2048 + mloc + col] =
                        *(const us8*)&SL[0][row * 136 + col];
                }
            }
        }
    }
}

// ---------------- O projection: fp32 out + bias, XCD-contiguous m-panels ----
__global__ __launch_bounds__(256, 4) void gemm_o(const unsigned short* __restrict__ A,
                                                 const unsigned short* __restrict__ B,
                                                 float* __restrict__ Cout,
                                                 const float* __restrict__ bias) {
    constexpr int KD = 1024;
    __shared__ __align__(16) unsigned short SL[2][8192];
    const int id = blockIdx.x;
    const int xcd = id & 7, j = id >> 3;           // j 0..63
    const int m0 = (xcd * 8 + (j & 7)) * 128;
    const int n0 = (j >> 3) * 128;
    const int tid = threadIdx.x;
    const int w = tid >> 6, l = tid & 63;
    const int lr = l & 15, lg = l >> 4;
    const int wm = (w >> 1) * 64, wn = (w & 1) * 64;

    f32x4 acc[4][4] = {};

    int ci0 = w * 64 + l;
    int r0 = ci0 >> 2, c0 = (ci0 & 3) ^ (r0 & 3);
    int ci1 = 256 + ci0;
    int r1 = ci1 >> 2, c1 = (ci1 & 3) ^ (r1 & 3);

    const unsigned short* Ag0 = A + (size_t)(m0 + r0) * KD + c0 * 8;
    const unsigned short* Ag1 = A + (size_t)(m0 + r1) * KD + c1 * 8;
    const unsigned short* Bg0 = B + (size_t)(n0 + r0) * KD + c0 * 8;
    const unsigned short* Bg1 = B + (size_t)(n0 + r1) * KD + c1 * 8;

#define STG(buf, k0)                                                  \
    do {                                                              \
        gload16(Ag0 + (k0), &SL[buf][w * 512]);                       \
        gload16(Ag1 + (k0), &SL[buf][2048 + w * 512]);                \
        gload16(Bg0 + (k0), &SL[buf][4096 + w * 512]);                \
        gload16(Bg1 + (k0), &SL[buf][4096 + 2048 + w * 512]);         \
    } while (0)

    constexpr int NT = KD >> 5;
    STG(0, 0);
    int buf = 0;
    for (int kt = 0; kt < NT; ++kt) {
        if (kt + 1 < NT) {
            STG(buf ^ 1, (kt + 1) * 32);
            asm volatile("s_waitcnt vmcnt(4)" ::: "memory");
        } else {
            asm volatile("s_waitcnt vmcnt(0)" ::: "memory");
        }
        __builtin_amdgcn_s_barrier();
        const unsigned short* Alc = &SL[buf][0];
        const unsigned short* Blc = &SL[buf][4096];
        bf16x8 af[4], bfr[4];
#pragma unroll
        for (int t = 0; t < 4; ++t) {
            int ar = wm + t * 16 + lr;
            af[t] = *(const bf16x8*)&Alc[ar * 32 + ((lg ^ (ar & 3)) * 8)];
            int br = wn + t * 16 + lr;
            bfr[t] = *(const bf16x8*)&Blc[br * 32 + ((lg ^ (br & 3)) * 8)];
        }
#pragma unroll
        for (int i = 0; i < 4; ++i)
#pragma unroll
            for (int jj = 0; jj < 4; ++jj)
                acc[i][jj] = mfma16(af[i], bfr[jj], acc[i][jj]);
        __builtin_amdgcn_s_barrier();
        buf ^= 1;
    }
#undef STG

#pragma unroll
    for (int i = 0; i < 4; ++i)
#pragma unroll
        for (int jj = 0; jj < 4; ++jj)
#pragma unroll
            for (int r = 0; r < 4; ++r) {
                int m = m0 + wm + i * 16 + lg * 4 + r;
                int n = n0 + wn + jj * 16 + lr;
                Cout[(size_t)m * 1024 + n] = acc[i][jj][r] + bias[n];
            }
}

// ---------------- flash attention, pipelined {QK(t+1) | PV(t) | exp2} -------
// No max-tracking (bounded logits, exp2 domain). K staged one tile ahead of V.
// STAGE_K/STAGE_V take TILE index: K tile stride = 64 rows * 64 d = 4096 elem;
// V (transposed) tile stride = 64 columns. (R6 bug: K used *64 — fixed *4096.)
__global__ __launch_bounds__(256, 3) void attn_fwd(const unsigned short* __restrict__ Q,
                                                   const unsigned short* __restrict__ K,
                                                   const unsigned short* __restrict__ VT,
                                                   unsigned short* __restrict__ O) {
    __shared__ __align__(16) unsigned short Kl[2][64 * 64];
    __shared__ __align__(16) unsigned short Vl[2][64 * 64];
    const int id = blockIdx.x;
    const int sw = (id & 7) * 128 + (id >> 3);   // bijective, 1024 % 8 == 0
    const int qt = sw & 15, bh = sw >> 4;
    const int tid = threadIdx.x;
    const int w = tid >> 6, l = tid & 63;
    const int lr = l & 15, lg = l >> 4;
    const size_t hbase = (size_t)bh * (2048 * 64);
    const size_t vbase = (size_t)bh * (64 * 2048);
    const int qbase = qt * 128 + w * 32;

    bf16x8 qf[2][2];
#pragma unroll
    for (int rt = 0; rt < 2; ++rt) {
        const unsigned short* qp = Q + hbase + (size_t)(qbase + rt * 16 + lr) * 64;
        qf[rt][0] = *(const bf16x8*)(qp + lg * 8);
        qf[rt][1] = *(const bf16x8*)(qp + 32 + lg * 8);
    }

    f32x4 oacc[2][4] = {};
    f32x4 lacc[2] = {};
    const f32x4 FZERO = {};
    f32x4 s[2][4];
    bf16x8 pa0[2], pa1[2];

    bf16x8 ONES;
#pragma unroll
    for (int e = 0; e < 8; ++e) ONES[e] = (__bf16)1.0f;

    const int cA = tid, cB = 256 + tid;
    const int krA = cA >> 3, kcA = (cA & 7) ^ (krA & 7);
    const int krB = cB >> 3, kcB = (cB & 7) ^ (krB & 7);
    const unsigned short* Kg0 = K + hbase + (size_t)krA * 64 + kcA * 8;
    const unsigned short* Kg1 = K + hbase + (size_t)krB * 64 + kcB * 8;
    const unsigned short* Vg0 = VT + vbase + (size_t)krA * 2048 + kcA * 8;
    const unsigned short* Vg1 = VT + vbase + (size_t)krB * 2048 + kcB * 8;

#define STAGE_K(dst, tkv)                                                     \
    do {                                                                      \
        gload16(Kg0 + (size_t)(tkv) * 4096, &Kl[dst][w * 512]);               \
        gload16(Kg1 + (size_t)(tkv) * 4096, &Kl[dst][2048 + w * 512]);        \
    } while (0)
#define STAGE_V(dst, tkv)                                                     \
    do {                                                                      \
        gload16(Vg0 + (size_t)(tkv) * 64, &Vl[dst][w * 512]);                 \
        gload16(Vg1 + (size_t)(tkv) * 64, &Vl[dst][2048 + w * 512]);          \
    } while (0)

    const int koff0 = lr * 64 + ((lg ^ (lr & 7)) * 8);
    const int koff1 = lr * 64 + (((4 + lg) ^ (lr & 7)) * 8);

#define QK_COMPUTE(Kc)                                                        \
    do {                                                                      \
        _Pragma("unroll")                                                     \
        for (int nt = 0; nt < 4; ++nt) {                                      \
            bf16x8 kf0 = *(const bf16x8*)&(Kc)[koff0 + nt * 1024];            \
            bf16x8 kf1 = *(const bf16x8*)&(Kc)[koff1 + nt * 1024];            \
            s[0][nt] = mfma16(kf0, qf[0][0], FZERO);                          \
            s[0][nt] = mfma16(kf1, qf[0][1], s[0][nt]);                       \
            s[1][nt] = mfma16(kf0, qf[1][0], FZERO);                          \
            s[1][nt] = mfma16(kf1, qf[1][1], s[1][nt]);                       \
        }                                                                     \
    } while (0)

#define EXP2_PACK                                                             \
    do {                                                                      \
        _Pragma("unroll")                                                     \
        for (int rt = 0; rt < 2; ++rt) {                                      \
            _Pragma("unroll")                                                 \
            for (int nt = 0; nt < 4; ++nt)                                    \
                _Pragma("unroll")                                             \
                for (int r = 0; r < 4; ++r)                                   \
                    s[rt][nt][r] = exp2v(s[rt][nt][r]);                       \
            _Pragma("unroll")                                                 \
            for (int e = 0; e < 4; ++e) {                                     \
                pa0[rt][e] = (__bf16)s[rt][0][e];                             \
                pa0[rt][4 + e] = (__bf16)s[rt][1][e];                         \
                pa1[rt][e] = (__bf16)s[rt][2][e];                             \
                pa1[rt][4 + e] = (__bf16)s[rt][3][e];                         \
            }                                                                 \
        }                                                                     \
    } while (0)

#define PV_COMPUTE(Vc)                                                        \
    do {                                                                      \
        lacc[0] = mfma16(pa0[0], ONES, lacc[0]);                              \
        lacc[0] = mfma16(pa1[0], ONES, lacc[0]);                              \
        lacc[1] = mfma16(pa0[1], ONES, lacc[1]);                              \
        lacc[1] = mfma16(pa1[1], ONES, lacc[1]);                              \
        _Pragma("unroll")                                                     \
        for (int nt = 0; nt < 4; ++nt) {                                      \
            bf16x8 vb0 = *(const bf16x8*)&(Vc)[koff0 + nt * 1024];            \
            bf16x8 vb1 = *(const bf16x8*)&(Vc)[koff1 + nt * 1024];            \
            oacc[0][nt] = mfma16(pa0[0], vb0, oacc[0][nt]);                   \
            oacc[0][nt] = mfma16(pa1[0], vb1, oacc[0][nt]);                   \
            oacc[1][nt] = mfma16(pa0[1], vb0, oacc[1][nt]);                   \
            oacc[1][nt] = mfma16(pa1[1], vb1, oacc[1][nt]);                   \
        }                                                                     \
    } while (0)

    // prologue: K(0) -> Kl[0]; QK(0); K(1),V(0) staged under it
    STAGE_K(0, 0);
    asm volatile("s_waitcnt vmcnt(0)" ::: "memory");
    __builtin_amdgcn_s_barrier();
    STAGE_K(1, 1);
    STAGE_V(0, 0);
    __builtin_amdgcn_s_setprio(1);
    QK_COMPUTE(Kl[0]);
    __builtin_amdgcn_s_setprio(0);
    EXP2_PACK;
    __builtin_amdgcn_s_barrier();

    for (int t = 0; t < 31; ++t) {
        if (t <= 29) STAGE_K(t & 1, t + 2);
        STAGE_V((t + 1) & 1, t + 1);
        if (t <= 29) {
            asm volatile("s_waitcnt vmcnt(4)" ::: "memory");
        } else {
            asm volatile("s_waitcnt vmcnt(2)" ::: "memory");
        }
        __builtin_amdgcn_s_barrier();
        __builtin_amdgcn_s_setprio(1);
        QK_COMPUTE(Kl[(t + 1) & 1]);   // -> s (next tile's logits)
        PV_COMPUTE(Vl[t & 1]);         // uses pa from previous tile
        __builtin_amdgcn_s_setprio(0);
        EXP2_PACK;                     // s -> pa, overlaps MFMA pipe drain
        __builtin_amdgcn_s_barrier();
    }

    asm volatile("s_waitcnt vmcnt(0)" ::: "memory");
    __builtin_amdgcn_s_barrier();
    __builtin_amdgcn_s_setprio(1);
    PV_COMPUTE(Vl[1]);                 // tile 31 (31&1 == 1)
    __builtin_amdgcn_s_setprio(0);

#undef STAGE_K
#undef STAGE_V
#undef QK_COMPUTE
#undef EXP2_PACK
#undef PV_COMPUTE

    const int b = bh >> 4, h = bh & 15;
#pragma unroll
    for (int rt = 0; rt < 2; ++rt)
#pragma unroll
        for (int r = 0; r < 4; ++r) {
            float inv = 1.0f / lacc[rt][r];
            int q = qbase + rt * 16 + lg * 4 + r;
            size_t rowbase = ((size_t)(b * 2048 + q)) * 1024 + h * 64;
#pragma unroll
            for (int nt = 0; nt < 4; ++nt)
                O[rowbase + nt * 16 + lr] = f2bf(oacc[rt][nt][r] * inv);
        }
}

// ----------------------------------------------------------------------------
extern "C" void kernel_launch(void* const* d_in, const int* in_sizes, int n_in,
                              void* d_out, int out_size, void* d_ws, size_t ws_size,
                              hipStream_t stream) {
    (void)in_sizes; (void)n_in; (void)out_size; (void)ws_size;
    const float* query = (const float*)d_in[0];
    const float* kv    = (const float*)d_in[1];
    const float* Wq    = (const float*)d_in[2];
    const float* Wk    = (const float*)d_in[3];
    const float* Wv    = (const float*)d_in[4];
    const float* Wo    = (const float*)d_in[5];
    const float* bo    = (const float*)d_in[6];
    float* out = (float*)d_out;

    // ws: qbf@0, kvbf@16M, weights 29.3M..36.7M, Qh@36.7M, Kh@53.4M,
    // VTh@70.25M (own region — merged proj reads qbf while writing VTh).
    // Ob aliases kvbf..WqT (all dead before attn; WoT@34.6M untouched).
    char* ws = (char*)d_ws;
    unsigned short* qbf  = (unsigned short*)(ws + 0);
    unsigned short* kvbf = (unsigned short*)(ws + 16777216);
    unsigned short* WkT  = (unsigned short*)(ws + 29360128);
    unsigned short* WvT  = (unsigned short*)(ws + 30932992);
    unsigned short* WqT  = (unsigned short*)(ws + 32505856);
    unsigned short* WoT  = (unsigned short*)(ws + 34603008);
    unsigned short* Qh   = (unsigned short*)(ws + 36700160);
    unsigned short* Kh   = (unsigned short*)(ws + 53477376);
    unsigned short* VTh  = (unsigned short*)(ws + 70254592);
    unsigned short* Ob   = (unsigned short*)(ws + 16777216);  // alias kvbf..

    const float QSCALE = 0.18033688011112042f;  // 0.125 * log2(e)

    conv2_bf16<<<7168, 256, 0, stream>>>(query, qbf, 1048576, kv, kvbf, 786432);
    wtrans_all<<<dim3(32, 112), dim3(32, 8), 0, stream>>>(Wq, Wk, Wv, Wo,
                                                          WqT, WkT, WvT, WoT, QSCALE);

    proj_qkv<<<1536, 256, 0, stream>>>(qbf, kvbf, WqT, WkT, WvT, Qh, Kh, VTh);
    attn_fwd<<<1024, 256, 0, stream>>>(Qh, Kh, VTh, Ob);
    gemm_o<<<512, 256, 0, stream>>>(Ob, WoT, out, bo);
}

// Round 8
// 161.784 us; speedup vs baseline: 1.0866x; 1.0866x over previous
//
#include <hip/hip_runtime.h>

typedef __attribute__((ext_vector_type(4))) float f32x4;
typedef __attribute__((ext_vector_type(8))) __bf16 bf16x8;
typedef __attribute__((ext_vector_type(8))) unsigned short us8;

__device__ __forceinline__ unsigned short f2bf(float f) {
    unsigned u = __builtin_bit_cast(unsigned, f);
    u += 0x7fffu + ((u >> 16) & 1u);
    return (unsigned short)(u >> 16);
}

__device__ __forceinline__ float exp2v(float x) {
    float r;
    asm("v_exp_f32 %0, %1" : "=v"(r) : "v"(x));
    return r;
}

__device__ __forceinline__ f32x4 mfma16(bf16x8 a, bf16x8 b, f32x4 c) {
    return __builtin_amdgcn_mfma_f32_16x16x32_bf16(a, b, c, 0, 0, 0);
}

__device__ __forceinline__ void gload16(const void* g, void* l) {
    __builtin_amdgcn_global_load_lds(
        (const __attribute__((address_space(1))) unsigned int*)g,
        (__attribute__((address_space(3))) unsigned int*)l, 16, 0, 0);
}

// ------------- fp32 -> bf16 convert, both inputs in one launch ---------------
__global__ __launch_bounds__(256) void conv2_bf16(const float* __restrict__ a,
                                                  unsigned short* __restrict__ oa,
                                                  int na8,
                                                  const float* __restrict__ b,
                                                  unsigned short* __restrict__ ob,
                                                  int nb8) {
    int i = blockIdx.x * 256 + threadIdx.x;
    const float* in;
    unsigned short* out;
    if (i < na8) {
        in = a; out = oa;
    } else {
        i -= na8;
        if (i >= nb8) return;
        in = b; out = ob;
    }
    const float4* p = (const float4*)in + (size_t)i * 2;
    float4 x = p[0], y = p[1];
    us8 o;
    o[0] = f2bf(x.x); o[1] = f2bf(x.y); o[2] = f2bf(x.z); o[3] = f2bf(x.w);
    o[4] = f2bf(y.x); o[5] = f2bf(y.y); o[6] = f2bf(y.z); o[7] = f2bf(y.w);
    *((us8*)out + i) = o;
}

// ------ all 4 weights: fp32 [R][1024] -> bf16 [1024][R], one launch ---------
__global__ __launch_bounds__(256) void wtrans_all(const float* __restrict__ Wq,
                                                  const float* __restrict__ Wk,
                                                  const float* __restrict__ Wv,
                                                  const float* __restrict__ Wo,
                                                  unsigned short* __restrict__ WqT,
                                                  unsigned short* __restrict__ WkT,
                                                  unsigned short* __restrict__ WvT,
                                                  unsigned short* __restrict__ WoT,
                                                  float qscale) {
    __shared__ float t[32][33];
    int y = blockIdx.y;
    const float* in; unsigned short* out; int R; float scale = 1.0f;
    if (y < 32)      { in = Wq; out = WqT; R = 1024; scale = qscale; }
    else if (y < 56) { in = Wk; out = WkT; R = 768;  y -= 32; }
    else if (y < 80) { in = Wv; out = WvT; R = 768;  y -= 56; }
    else             { in = Wo; out = WoT; R = 1024; y -= 80; }
    int tx = threadIdx.x, ty = threadIdx.y;
    int r0 = y * 32, c0 = blockIdx.x * 32;
#pragma unroll
    for (int k = 0; k < 4; ++k)
        t[ty + k * 8][tx] = in[(size_t)(r0 + ty + k * 8) * 1024 + c0 + tx];
    __syncthreads();
#pragma unroll
    for (int k = 0; k < 4; ++k)
        out[(size_t)(c0 + ty + k * 8) * R + r0 + tx] = f2bf(t[tx][ty + k * 8] * scale);
}

// ---- merged Q/K/V projection, XCD-contiguous m-panels, 128x128 tiles -------
__global__ __launch_bounds__(256, 4) void proj_qkv(const unsigned short* __restrict__ qbf,
                                                   const unsigned short* __restrict__ kvbf,
                                                   const unsigned short* __restrict__ WqT,
                                                   const unsigned short* __restrict__ WkT,
                                                   const unsigned short* __restrict__ WvT,
                                                   unsigned short* __restrict__ Qh,
                                                   unsigned short* __restrict__ Kh,
                                                   unsigned short* __restrict__ VTh) {
    __shared__ __align__(16) unsigned short SL[2][8192];
    const int id = blockIdx.x;
    const int xcd = id & 7, j = id >> 3;
    const int my = xcd * 8 + (j & 7);
    const int rest = j >> 3;          // 0..23
    const int op = rest >> 3;         // 0:Q 1:K 2:V
    const int nx = rest & 7;
    const int m0 = my * 128, n0 = nx * 128;
    const unsigned short* A = (op == 0) ? qbf : kvbf;
    const unsigned short* B = (op == 0) ? WqT : (op == 1 ? WkT : WvT);
    const int KD = (op == 0) ? 1024 : 768;
    const int NT = KD >> 5;

    const int tid = threadIdx.x;
    const int w = tid >> 6, l = tid & 63;
    const int lr = l & 15, lg = l >> 4;
    const int wm = (w >> 1) * 64, wn = (w & 1) * 64;

    f32x4 acc[4][4] = {};

    int ci0 = w * 64 + l;
    int r0 = ci0 >> 2, c0 = (ci0 & 3) ^ (r0 & 3);
    int ci1 = 256 + ci0;
    int r1 = ci1 >> 2, c1 = (ci1 & 3) ^ (r1 & 3);

    const unsigned short* Ag0 = A + (size_t)(m0 + r0) * KD + c0 * 8;
    const unsigned short* Ag1 = A + (size_t)(m0 + r1) * KD + c1 * 8;
    const unsigned short* Bg0 = B + (size_t)(n0 + r0) * KD + c0 * 8;
    const unsigned short* Bg1 = B + (size_t)(n0 + r1) * KD + c1 * 8;

#define STG(buf, k0)                                                  \
    do {                                                              \
        gload16(Ag0 + (k0), &SL[buf][w * 512]);                       \
        gload16(Ag1 + (k0), &SL[buf][2048 + w * 512]);                \
        gload16(Bg0 + (k0), &SL[buf][4096 + w * 512]);                \
        gload16(Bg1 + (k0), &SL[buf][4096 + 2048 + w * 512]);         \
    } while (0)

    STG(0, 0);
    int buf = 0;
    for (int kt = 0; kt < NT; ++kt) {
        if (kt + 1 < NT) {
            STG(buf ^ 1, (kt + 1) * 32);
            asm volatile("s_waitcnt vmcnt(4)" ::: "memory");
        } else {
            asm volatile("s_waitcnt vmcnt(0)" ::: "memory");
        }
        __builtin_amdgcn_s_barrier();
        const unsigned short* Alc = &SL[buf][0];
        const unsigned short* Blc = &SL[buf][4096];
        bf16x8 af[4], bfr[4];
#pragma unroll
        for (int t = 0; t < 4; ++t) {
            int ar = wm + t * 16 + lr;
            af[t] = *(const bf16x8*)&Alc[ar * 32 + ((lg ^ (ar & 3)) * 8)];
            int br = wn + t * 16 + lr;
            bfr[t] = *(const bf16x8*)&Blc[br * 32 + ((lg ^ (br & 3)) * 8)];
        }
#pragma unroll
        for (int i = 0; i < 4; ++i)
#pragma unroll
            for (int jj = 0; jj < 4; ++jj)
                acc[i][jj] = mfma16(af[i], bfr[jj], acc[i][jj]);
        __builtin_amdgcn_s_barrier();
        buf ^= 1;
    }
#undef STG

    if (op != 2) {
        unsigned short* Cout = (op == 0) ? Qh : Kh;
#pragma unroll
        for (int i = 0; i < 4; ++i)
#pragma unroll
            for (int jj = 0; jj < 4; ++jj)
#pragma unroll
                for (int r = 0; r < 4; ++r) {
                    int m = m0 + wm + i * 16 + lg * 4 + r;
                    int n = n0 + wn + jj * 16 + lr;
                    int b = m >> 11, ql = m & 2047, h = n >> 6, d = n & 63;
                    Cout[(((size_t)(b * 16 + h) * 2048 + ql) << 6) + d] = f2bf(acc[i][jj][r]);
                }
    } else {
        // V: transpose via LDS -> VT [bh][64d][2048kv], pi-permuted on kv.
        const int b = m0 >> 11;
        const int mloc = m0 & 2047;
        const int h0 = n0 >> 6;
#pragma unroll
        for (int hp = 0; hp < 2; ++hp) {
            unsigned short* VTb = VTh + (size_t)(b * 16 + h0 + hp) * (64 * 2048);
#pragma unroll
            for (int dh = 0; dh < 2; ++dh) {
                __syncthreads();
                if ((w & 1) == hp) {
#pragma unroll
                    for (int jj = 0; jj < 2; ++jj) {
                        int jc = dh * 2 + jj;
                        int dl = jj * 16 + lr;
#pragma unroll
                        for (int i = 0; i < 4; ++i)
#pragma unroll
                            for (int r = 0; r < 4; ++r) {
                                int kvl = wm + i * 16 + lg * 4 + r;
                                int pl = (kvl & 0x60) | (((kvl >> 2) & 3) << 3) |
                                         (((kvl >> 4) & 1) << 2) | (kvl & 3);
                                SL[0][dl * 136 + pl] = f2bf(acc[i][jc][r]);
                            }
                    }
                }
                __syncthreads();
#pragma unroll
                for (int cc = 0; cc < 2; ++cc) {
                    int idx = cc * 256 + tid;
                    int row = idx >> 4, col = (idx & 15) * 8;
                    *(us8*)&VTb[(size_t)(dh * 32 + row) * 2048 + mloc + col] =
                        *(const us8*)&SL[0][row * 136 + col];
                }
            }
        }
    }
}

// ---------------- O projection: fp32 out + bias, XCD-contiguous m-panels ----
__global__ __launch_bounds__(256, 4) void gemm_o(const unsigned short* __restrict__ A,
                                                 const unsigned short* __restrict__ B,
                                                 float* __restrict__ Cout,
                                                 const float* __restrict__ bias) {
    constexpr int KD = 1024;
    __shared__ __align__(16) unsigned short SL[2][8192];
    const int id = blockIdx.x;
    const int xcd = id & 7, j = id >> 3;           // j 0..63
    const int m0 = (xcd * 8 + (j & 7)) * 128;
    const int n0 = (j >> 3) * 128;
    const int tid = threadIdx.x;
    const int w = tid >> 6, l = tid & 63;
    const int lr = l & 15, lg = l >> 4;
    const int wm = (w >> 1) * 64, wn = (w & 1) * 64;

    f32x4 acc[4][4] = {};

    int ci0 = w * 64 + l;
    int r0 = ci0 >> 2, c0 = (ci0 & 3) ^ (r0 & 3);
    int ci1 = 256 + ci0;
    int r1 = ci1 >> 2, c1 = (ci1 & 3) ^ (r1 & 3);

    const unsigned short* Ag0 = A + (size_t)(m0 + r0) * KD + c0 * 8;
    const unsigned short* Ag1 = A + (size_t)(m0 + r1) * KD + c1 * 8;
    const unsigned short* Bg0 = B + (size_t)(n0 + r0) * KD + c0 * 8;
    const unsigned short* Bg1 = B + (size_t)(n0 + r1) * KD + c1 * 8;

#define STG(buf, k0)                                                  \
    do {                                                              \
        gload16(Ag0 + (k0), &SL[buf][w * 512]);                       \
        gload16(Ag1 + (k0), &SL[buf][2048 + w * 512]);                \
        gload16(Bg0 + (k0), &SL[buf][4096 + w * 512]);                \
        gload16(Bg1 + (k0), &SL[buf][4096 + 2048 + w * 512]);         \
    } while (0)

    constexpr int NT = KD >> 5;
    STG(0, 0);
    int buf = 0;
    for (int kt = 0; kt < NT; ++kt) {
        if (kt + 1 < NT) {
            STG(buf ^ 1, (kt + 1) * 32);
            asm volatile("s_waitcnt vmcnt(4)" ::: "memory");
        } else {
            asm volatile("s_waitcnt vmcnt(0)" ::: "memory");
        }
        __builtin_amdgcn_s_barrier();
        const unsigned short* Alc = &SL[buf][0];
        const unsigned short* Blc = &SL[buf][4096];
        bf16x8 af[4], bfr[4];
#pragma unroll
        for (int t = 0; t < 4; ++t) {
            int ar = wm + t * 16 + lr;
            af[t] = *(const bf16x8*)&Alc[ar * 32 + ((lg ^ (ar & 3)) * 8)];
            int br = wn + t * 16 + lr;
            bfr[t] = *(const bf16x8*)&Blc[br * 32 + ((lg ^ (br & 3)) * 8)];
        }
#pragma unroll
        for (int i = 0; i < 4; ++i)
#pragma unroll
            for (int jj = 0; jj < 4; ++jj)
                acc[i][jj] = mfma16(af[i], bfr[jj], acc[i][jj]);
        __builtin_amdgcn_s_barrier();
        buf ^= 1;
    }
#undef STG

#pragma unroll
    for (int i = 0; i < 4; ++i)
#pragma unroll
        for (int jj = 0; jj < 4; ++jj)
#pragma unroll
            for (int r = 0; r < 4; ++r) {
                int m = m0 + wm + i * 16 + lg * 4 + r;
                int n = n0 + wn + jj * 16 + lr;
                Cout[(size_t)m * 1024 + n] = acc[i][jj][r] + bias[n];
            }
}

// ---------------- flash attention: R5 schedule, QBLK=64 per wave (RT=4) -----
// Per tile: 8 K-frag ds_reads feed 32 QK MFMA; 64 exp2; 8 V-frag reads feed
// 32 PV MFMA + 8 lacc MFMA. Fixed costs (staging/barriers/ds_read) amortized
// 2x vs R5. No max-tracking (bounded logits, exp2 domain). Grid 512, 2 blk/CU.
__global__ __launch_bounds__(256, 2) void attn_fwd(const unsigned short* __restrict__ Q,
                                                   const unsigned short* __restrict__ K,
                                                   const unsigned short* __restrict__ VT,
                                                   unsigned short* __restrict__ O) {
    __shared__ __align__(16) unsigned short Kl[2][64 * 64];
    __shared__ __align__(16) unsigned short Vl[2][64 * 64];
    const int id = blockIdx.x;
    const int sw = (id & 7) * 64 + (id >> 3);   // bijective, 512 % 8 == 0
    const int qt = sw & 7, bh = sw >> 3;        // 8 heads per XCD (L2-resident K/V)
    const int tid = threadIdx.x;
    const int w = tid >> 6, l = tid & 63;
    const int lr = l & 15, lg = l >> 4;
    const size_t hbase = (size_t)bh * (2048 * 64);
    const size_t vbase = (size_t)bh * (64 * 2048);
    const int qbase = qt * 256 + w * 64;

    bf16x8 qf[4][2];
#pragma unroll
    for (int rt = 0; rt < 4; ++rt) {
        const unsigned short* qp = Q + hbase + (size_t)(qbase + rt * 16 + lr) * 64;
        qf[rt][0] = *(const bf16x8*)(qp + lg * 8);
        qf[rt][1] = *(const bf16x8*)(qp + 32 + lg * 8);
    }

    f32x4 oacc[4][4] = {};
    f32x4 lacc[4] = {};
    const f32x4 FZERO = {};

    bf16x8 ONES;
#pragma unroll
    for (int e = 0; e < 8; ++e) ONES[e] = (__bf16)1.0f;

    const int cA = tid, cB = 256 + tid;
    const int krA = cA >> 3, kcA = (cA & 7) ^ (krA & 7);
    const int krB = cB >> 3, kcB = (cB & 7) ^ (krB & 7);
    const unsigned short* Kg0 = K + hbase + (size_t)krA * 64 + kcA * 8;
    const unsigned short* Kg1 = K + hbase + (size_t)krB * 64 + kcB * 8;
    const unsigned short* Vg0 = VT + vbase + (size_t)krA * 2048 + kcA * 8;
    const unsigned short* Vg1 = VT + vbase + (size_t)krB * 2048 + kcB * 8;

// kv0 is the kv ELEMENT offset of the tile (R5 convention).
#define STAGE_KV(dst, kv0)                                                    \
    do {                                                                      \
        gload16(Kg0 + (size_t)(kv0) * 64, &Kl[dst][w * 512]);                 \
        gload16(Kg1 + (size_t)(kv0) * 64, &Kl[dst][2048 + w * 512]);          \
        gload16(Vg0 + (kv0), &Vl[dst][w * 512]);                              \
        gload16(Vg1 + (kv0), &Vl[dst][2048 + w * 512]);                       \
    } while (0)

    const int koff0 = lr * 64 + ((lg ^ (lr & 7)) * 8);
    const int koff1 = lr * 64 + (((4 + lg) ^ (lr & 7)) * 8);

    STAGE_KV(0, 0);
    int cur = 0;

    for (int t = 0; t < 32; ++t) {
        if (t < 31) {
            STAGE_KV(cur ^ 1, (t + 1) * 64);
            asm volatile("s_waitcnt vmcnt(4)" ::: "memory");
        } else {
            asm volatile("s_waitcnt vmcnt(0)" ::: "memory");
        }
        __builtin_amdgcn_s_barrier();
        const unsigned short* Kc = Kl[cur];
        const unsigned short* Vc = Vl[cur];

        // S^T = K Q^T  (lane: q = lr within rt-tile; kv = nt*16 + lg*4 + r)
        f32x4 s[4][4];
        __builtin_amdgcn_s_setprio(1);
#pragma unroll
        for (int nt = 0; nt < 4; ++nt) {
            bf16x8 kf0 = *(const bf16x8*)&Kc[koff0 + nt * 1024];
            bf16x8 kf1 = *(const bf16x8*)&Kc[koff1 + nt * 1024];
#pragma unroll
            for (int rt = 0; rt < 4; ++rt) {
                s[rt][nt] = mfma16(kf0, qf[rt][0], FZERO);
                s[rt][nt] = mfma16(kf1, qf[rt][1], s[rt][nt]);
            }
        }
        __builtin_amdgcn_s_setprio(0);

        // P = exp2(S) directly (bounded logits), pack into PV A-fragments
        bf16x8 pa0[4], pa1[4];
#pragma unroll
        for (int rt = 0; rt < 4; ++rt) {
#pragma unroll
            for (int nt = 0; nt < 4; ++nt)
#pragma unroll
                for (int r = 0; r < 4; ++r)
                    s[rt][nt][r] = exp2v(s[rt][nt][r]);
#pragma unroll
            for (int e = 0; e < 4; ++e) {
                pa0[rt][e] = (__bf16)s[rt][0][e];
                pa0[rt][4 + e] = (__bf16)s[rt][1][e];
                pa1[rt][e] = (__bf16)s[rt][2][e];
                pa1[rt][4 + e] = (__bf16)s[rt][3][e];
            }
        }

        __builtin_amdgcn_s_setprio(1);
#pragma unroll
        for (int rt = 0; rt < 4; ++rt) {
            lacc[rt] = mfma16(pa0[rt], ONES, lacc[rt]);
            lacc[rt] = mfma16(pa1[rt], ONES, lacc[rt]);
        }
#pragma unroll
        for (int nt = 0; nt < 4; ++nt) {
            bf16x8 vb0 = *(const bf16x8*)&Vc[koff0 + nt * 1024];
            bf16x8 vb1 = *(const bf16x8*)&Vc[koff1 + nt * 1024];
#pragma unroll
            for (int rt = 0; rt < 4; ++rt) {
                oacc[rt][nt] = mfma16(pa0[rt], vb0, oacc[rt][nt]);
                oacc[rt][nt] = mfma16(pa1[rt], vb1, oacc[rt][nt]);
            }
        }
        __builtin_amdgcn_s_setprio(0);
        __builtin_amdgcn_s_barrier();
        cur ^= 1;
    }
#undef STAGE_KV

    const int b = bh >> 4, h = bh & 15;
#pragma unroll
    for (int rt = 0; rt < 4; ++rt)
#pragma unroll
        for (int r = 0; r < 4; ++r) {
            float inv = 1.0f / lacc[rt][r];
            int q = qbase + rt * 16 + lg * 4 + r;
            size_t rowbase = ((size_t)(b * 2048 + q)) * 1024 + h * 64;
#pragma unroll
            for (int nt = 0; nt < 4; ++nt)
                O[rowbase + nt * 16 + lr] = f2bf(oacc[rt][nt][r] * inv);
        }
}

// ----------------------------------------------------------------------------
extern "C" void kernel_launch(void* const* d_in, const int* in_sizes, int n_in,
                              void* d_out, int out_size, void* d_ws, size_t ws_size,
                              hipStream_t stream) {
    (void)in_sizes; (void)n_in; (void)out_size; (void)ws_size;
    const float* query = (const float*)d_in[0];
    const float* kv    = (const float*)d_in[1];
    const float* Wq    = (const float*)d_in[2];
    const float* Wk    = (const float*)d_in[3];
    const float* Wv    = (const float*)d_in[4];
    const float* Wo    = (const float*)d_in[5];
    const float* bo    = (const float*)d_in[6];
    float* out = (float*)d_out;

    char* ws = (char*)d_ws;
    unsigned short* qbf  = (unsigned short*)(ws + 0);
    unsigned short* kvbf = (unsigned short*)(ws + 16777216);
    unsigned short* WkT  = (unsigned short*)(ws + 29360128);
    unsigned short* WvT  = (unsigned short*)(ws + 30932992);
    unsigned short* WqT  = (unsigned short*)(ws + 32505856);
    unsigned short* WoT  = (unsigned short*)(ws + 34603008);
    unsigned short* Qh   = (unsigned short*)(ws + 36700160);
    unsigned short* Kh   = (unsigned short*)(ws + 53477376);
    unsigned short* VTh  = (unsigned short*)(ws + 70254592);
    unsigned short* Ob   = (unsigned short*)(ws + 16777216);  // alias kvbf..

    const float QSCALE = 0.18033688011112042f;  // 0.125 * log2(e)

    conv2_bf16<<<7168, 256, 0, stream>>>(query, qbf, 1048576, kv, kvbf, 786432);
    wtrans_all<<<dim3(32, 112), dim3(32, 8), 0, stream>>>(Wq, Wk, Wv, Wo,
                                                          WqT, WkT, WvT, WoT, QSCALE);

    proj_qkv<<<1536, 256, 0, stream>>>(qbf, kvbf, WqT, WkT, WvT, Qh, Kh, VTh);
    attn_fwd<<<512, 256, 0, stream>>>(Qh, Kh, VTh, Ob);
    gemm_o<<<512, 256, 0, stream>>>(Ob, WoT, out, bo);
}